// Round 5
// baseline (3138.895 us; speedup 1.0000x reference)
//
#include <hip/hip_runtime.h>

#define BB 16
#define LL 2048
#define HH 512
#define NN2 32
#define NLAY 4
#define OUTD 256
#define BLM (BB*LL)                 // 32768 rows
#define NELEM ((size_t)BLM*HH)      // 16.78M activations
#define NC 16                       // SSM time chunks
#define LC (LL/NC)                  // 128
#define LGLC 7                      // log2(LC)

typedef __attribute__((ext_vector_type(8))) short s8v;   // 8 bf16 (4 VGPR)
typedef __attribute__((ext_vector_type(4))) float f4v;   // MFMA acc

__device__ __forceinline__ unsigned short f2bf(float f) {
  unsigned u = __float_as_uint(f);
  return (unsigned short)((u + 0x7fffu + ((u >> 16) & 1u)) >> 16);  // RNE
}
__device__ __forceinline__ float bf2f(unsigned short h) {
  return __uint_as_float((unsigned)h << 16);
}
__device__ __forceinline__ void gload16(const void* g, void* l) {
  __builtin_amdgcn_global_load_lds(
      (const __attribute__((address_space(1))) unsigned int*)g,
      (__attribute__((address_space(3))) unsigned int*)l, 16, 0, 0);
}

// ---------------- embedding gather -> bf16 hi/lo split ---------------------
__global__ __launch_bounds__(256) void k_embed(const int* __restrict__ x,
    const float* __restrict__ emb, unsigned short* __restrict__ Ahi,
    unsigned short* __restrict__ Alo) {
  int idx = blockIdx.x * 256 + threadIdx.x;      // one float4-group
  int j4 = idx & 127;
  int bl = idx >> 7;
  int tok = x[bl];
  float4 v = reinterpret_cast<const float4*>(emb)[tok * 128 + j4];
  unsigned short h0 = f2bf(v.x), h1 = f2bf(v.y), h2 = f2bf(v.z), h3 = f2bf(v.w);
  unsigned short l0 = f2bf(v.x - bf2f(h0)), l1 = f2bf(v.y - bf2f(h1));
  unsigned short l2 = f2bf(v.z - bf2f(h2)), l3 = f2bf(v.w - bf2f(h3));
  uint2 hp = make_uint2((unsigned)h0 | ((unsigned)h1 << 16),
                        (unsigned)h2 | ((unsigned)h3 << 16));
  uint2 lp = make_uint2((unsigned)l0 | ((unsigned)l1 << 16),
                        (unsigned)l2 | ((unsigned)l3 << 16));
  *reinterpret_cast<uint2*>(&Ahi[(size_t)idx * 4]) = hp;
  *reinterpret_cast<uint2*>(&Alo[(size_t)idx * 4]) = lp;
}

// ---------------- weight transpose + hi/lo split: Wt[n][k] = W[k][n] -------
__global__ __launch_bounds__(256) void k_trans(const float* __restrict__ W, int N,
    unsigned short* __restrict__ th, unsigned short* __restrict__ tl) {
  int t = blockIdx.x * 256 + threadIdx.x;        // over N*512, k fastest
  int k = t & 511, n = t >> 9;
  float v = W[(size_t)k * N + n];
  unsigned short hi = f2bf(v);
  th[(size_t)n * 512 + k] = hi;
  tl[(size_t)n * 512 + k] = f2bf(v - bf2f(hi));
}

// ---------------- per-layer SSM parameters; par laid out [n][h] ------------
__global__ __launch_bounds__(256) void k_params(const float* __restrict__ log_dt,
    const float* __restrict__ log_A_real, const float* __restrict__ A_imag,
    const float* __restrict__ C_re, const float* __restrict__ C_im,
    int layer, float4* __restrict__ par) {
  int idx = blockIdx.x * 256 + threadIdx.x;      // h*32+n
  int h = idx >> 5, n = idx & 31;
  int o = layer * HH * NN2 + idx;
  float dt  = expf(log_dt[layer * HH + h]);
  float Are = -expf(log_A_real[o]);
  float Aim = A_imag[o];
  float er = expf(Are * dt);
  float lr = er * cosf(Aim * dt), li = er * sinf(Aim * dt);
  float inv  = 1.0f / (Are * Are + Aim * Aim);
  float numr = lr - 1.0f, numi = li;
  float qr = (numr * Are + numi * Aim) * inv;
  float qi = (numi * Are - numr * Aim) * inv;
  float cr = C_re[o], ci = C_im[o];
  par[n * HH + h] = make_float4(lr, li, 2.0f * (cr * qr - ci * qi),
                                        2.0f * (cr * qi + ci * qr));
}

// ---------------- split-bf16 MFMA GEMM, 128x128 tile, BK=32, double-buffered
template<int EPI>
__global__ __launch_bounds__(256) void k_gemm(
    const unsigned short* __restrict__ Ahi, const unsigned short* __restrict__ Alo,
    const unsigned short* __restrict__ Bhi, const unsigned short* __restrict__ Blo,
    const float* __restrict__ bias, float* __restrict__ Out, int N) {
  __shared__ short lds[32768];                   // 64KB: 2 x (AH|AL|BH|BL)
  const int tid = threadIdx.x;
  const int lane = tid & 63, w = tid >> 6;
  const int wr = w >> 1, wc = w & 1;             // wave -> 64x64 quadrant
  const int m0 = blockIdx.y * 128, n0 = blockIdx.x * 128;
  const int lm = lane & 15, lk = lane >> 4;

  const unsigned short* ga[2][2]; const unsigned short* gb[2][2];
  short *da[2][2], *db[2][2];
#pragma unroll
  for (int f2 = 0; f2 < 2; ++f2) {
    int f = w * 2 + f2;                          // frag 0..7
    size_t ra = (size_t)(m0 + f * 16 + lm) * 512 + lk * 8;
    size_t rb = (size_t)(n0 + f * 16 + lm) * 512 + lk * 8;
    ga[0][f2] = Ahi + ra; ga[1][f2] = Alo + ra;
    gb[0][f2] = Bhi + rb; gb[1][f2] = Blo + rb;
    da[0][f2] = &lds[f * 512 + lane * 8];
    da[1][f2] = &lds[4096 + f * 512 + lane * 8];
    db[0][f2] = &lds[8192 + f * 512 + lane * 8];
    db[1][f2] = &lds[12288 + f * 512 + lane * 8];
  }
  f4v acc[4][4];
#pragma unroll
  for (int i = 0; i < 4; ++i)
#pragma unroll
    for (int j = 0; j < 4; ++j) acc[i][j] = (f4v){0.f, 0.f, 0.f, 0.f};

  auto stage = [&](int kt, int bofs) {
#pragma unroll
    for (int f2 = 0; f2 < 2; ++f2) {
      gload16(ga[0][f2] + kt * 32, da[0][f2] + bofs);
      gload16(ga[1][f2] + kt * 32, da[1][f2] + bofs);
      gload16(gb[0][f2] + kt * 32, db[0][f2] + bofs);
      gload16(gb[1][f2] + kt * 32, db[1][f2] + bofs);
    }
  };
  auto compute = [&](int bofs) {
    s8v ah[4], al[4], bh[4], bl[4];
#pragma unroll
    for (int i = 0; i < 4; ++i) {
      ah[i] = *(const s8v*)&lds[bofs + (wr * 4 + i) * 512 + lane * 8];
      al[i] = *(const s8v*)&lds[bofs + 4096 + (wr * 4 + i) * 512 + lane * 8];
      bh[i] = *(const s8v*)&lds[bofs + 8192 + (wc * 4 + i) * 512 + lane * 8];
      bl[i] = *(const s8v*)&lds[bofs + 12288 + (wc * 4 + i) * 512 + lane * 8];
    }
#pragma unroll
    for (int mi = 0; mi < 4; ++mi)
#pragma unroll
      for (int ni = 0; ni < 4; ++ni) {
        acc[mi][ni] = __builtin_amdgcn_mfma_f32_16x16x32_bf16(ah[mi], bh[ni], acc[mi][ni], 0, 0, 0);
        acc[mi][ni] = __builtin_amdgcn_mfma_f32_16x16x32_bf16(al[mi], bh[ni], acc[mi][ni], 0, 0, 0);
        acc[mi][ni] = __builtin_amdgcn_mfma_f32_16x16x32_bf16(ah[mi], bl[ni], acc[mi][ni], 0, 0, 0);
      }
  };

  stage(0, 0);
  __syncthreads();                               // tile 0 ready
#pragma unroll 1
  for (int t = 0; t < 8; ++t) {
    stage(2 * t + 1, 16384);                     // prefetch odd tile
    compute(0);                                  // compute even tile
    __syncthreads();                             // drains prefetch vmcnt
    if (t < 7) stage(2 * t + 2, 0);              // prefetch next even tile
    compute(16384);                              // compute odd tile
    __syncthreads();
  }
  // epilogue: C/D layout col=lane&15, row=(lane>>4)*4+reg
  float bb[4];
#pragma unroll
  for (int ni = 0; ni < 4; ++ni) bb[ni] = bias[n0 + wc * 64 + ni * 16 + lm];
#pragma unroll
  for (int mi = 0; mi < 4; ++mi) {
#pragma unroll
    for (int r = 0; r < 4; ++r) {
      int row = m0 + wr * 64 + mi * 16 + lk * 4 + r;
      float* po = Out + (size_t)row * N;
      const unsigned short* ph = Ahi + (size_t)row * 512;
      const unsigned short* pl = Alo + (size_t)row * 512;
#pragma unroll
      for (int ni = 0; ni < 4; ++ni) {
        int col = n0 + wc * 64 + ni * 16 + lm;
        float t = acc[mi][ni][r] + bb[ni];
        if (EPI) {
          t += bf2f(ph[col]) + bf2f(pl[col]);     // resid = hi+lo (err 2^-18)
          t = t < 0.f ? 2.f * t : 4.f * t;        // relu+res, x2
        }
        po[col] = t;
      }
    }
  }
}

// ---------------- SSM pass A: thread=(b,c,h), 32 states in regs ------------
// coalesced u loads (lane = h); chunk-local raw end state -> st[b][c][n][h]
__global__ __launch_bounds__(256, 2) void k_sa(const float* __restrict__ U,
    const float4* __restrict__ par, float2* __restrict__ st) {
  int h = (blockIdx.x << 8) + threadIdx.x;       // grid.x = 2
  int c = blockIdx.y, b = blockIdx.z;            // c in 0..NC-2
  float lr[32], li[32], gr[32], gi[32];
#pragma unroll
  for (int n = 0; n < 32; ++n) {
    float4 p = par[n * HH + h];
    lr[n] = p.x; li[n] = p.y; gr[n] = 0.f; gi[n] = 0.f;
  }
  const float* Up = U + ((size_t)b * LL + (size_t)c * LC) * HH + h;
  auto step = [&](float uv) {
#pragma unroll
    for (int n = 0; n < 32; ++n) {
      float ngr = fmaf(lr[n], gr[n], fmaf(-li[n], gi[n], uv));
      gi[n] = fmaf(lr[n], gi[n], li[n] * gr[n]);
      gr[n] = ngr;
    }
  };
  float u0 = Up[0], u1 = Up[HH], u2 = Up[2 * HH], u3 = Up[3 * HH];
  for (int lg = 0; lg < LC / 4; ++lg) {
    const float* nx = Up + (size_t)(lg * 4 + 4) * HH;  // c<=NC-2: stays in U
    float v0 = nx[0], v1 = nx[HH], v2 = nx[2 * HH], v3 = nx[3 * HH];
    step(u0); step(u1); step(u2); step(u3);
    u0 = v0; u1 = v1; u2 = v2; u3 = v3;
  }
  size_t so = ((size_t)b * (NC - 1) + c) * (NN2 * HH) + h;
#pragma unroll
  for (int n = 0; n < 32; ++n)
    st[so + (size_t)n * HH] = make_float2(gr[n], gi[n]);
}

// ---------------- fold: prefix-scan chunk states (in place, shifted) -------
// st layout [b][c][n][h]; after: slot c holds raw state at START of chunk c+1.
__global__ __launch_bounds__(256) void k_fold(const float4* __restrict__ par,
    float2* __restrict__ st) {
  int t = blockIdx.x * 256 + threadIdx.x;        // b*16384 + n*512 + h
  int r = t & 16383;
  int b = t >> 14;
  float4 p = par[r];                             // par is [n][h] -> index r
  float ar = p.x, ai = p.y;
#pragma unroll
  for (int s = 0; s < LGLC; ++s) { float nr = ar * ar - ai * ai; ai = 2.f * ar * ai; ar = nr; }  // lam^LC
  float gr = 0.f, gi = 0.f;
  size_t idx = (size_t)b * (NC - 1) * 16384 + r;
  for (int c = 0; c < NC - 1; ++c) {
    float2 s = st[idx + (size_t)c * 16384];
    float ngr = fmaf(ar, gr, fmaf(-ai, gi, s.x));
    gi = fmaf(ar, gi, fmaf(ai, gr, s.y));
    gr = ngr;
    st[idx + (size_t)c * 16384] = make_float2(gr, gi);
  }
}

// ---------------- SSM pass B: thread=(b,c,h), 32 states, no cross-lane -----
// t = (2coef)*g recurrence; y = Sum Re t; out = act2(y + (D+1)u) -> bf16 hi/lo
__global__ __launch_bounds__(256, 2) void k_sb(const float* __restrict__ U,
    const float4* __restrict__ par, const float2* __restrict__ st,
    const float* __restrict__ D, unsigned short* __restrict__ Hhi,
    unsigned short* __restrict__ Hlo) {
  int h = (blockIdx.x << 8) + threadIdx.x;       // grid.x = 2
  int c = blockIdx.y, b = blockIdx.z;            // c in 0..NC-1
  float lr[32], li[32], cr[32], ci[32], tr[32], ti[32];
#pragma unroll
  for (int n = 0; n < 32; ++n) {
    float4 p = par[n * HH + h];
    lr[n] = p.x; li[n] = p.y; cr[n] = p.z; ci[n] = p.w;
    tr[n] = 0.f; ti[n] = 0.f;
  }
  if (c > 0) {
    size_t so = ((size_t)b * (NC - 1) + (c - 1)) * (NN2 * HH) + h;
#pragma unroll
    for (int n = 0; n < 32; ++n) {
      float2 s = st[so + (size_t)n * HH];
      tr[n] = cr[n] * s.x - ci[n] * s.y;
      ti[n] = cr[n] * s.y + ci[n] * s.x;
    }
  }
  float dp1 = D[h] + 1.0f;
  size_t base = ((size_t)b * LL + (size_t)c * LC) * HH + h;
  const float* Up = U + base;
  unsigned short* Hh = Hhi + base;
  unsigned short* Hl = Hlo + base;
  auto step = [&](float uv) -> float {
    float y0 = 0.f, y1 = 0.f, y2 = 0.f, y3 = 0.f;
#pragma unroll
    for (int n = 0; n < 32; ++n) {
      float ntr = fmaf(lr[n], tr[n], fmaf(-li[n], ti[n], cr[n] * uv));
      ti[n] = fmaf(lr[n], ti[n], fmaf(li[n], tr[n], ci[n] * uv));
      tr[n] = ntr;
      if ((n & 3) == 0) y0 += ntr; else if ((n & 3) == 1) y1 += ntr;
      else if ((n & 3) == 2) y2 += ntr; else y3 += ntr;
    }
    float t4 = fmaf(dp1, uv, (y0 + y1) + (y2 + y3));
    return t4 < 0.f ? 2.f * t4 : 4.f * t4;
  };
  float u0 = Up[0], u1 = Up[HH], u2 = Up[2 * HH], u3 = Up[3 * HH];
  for (int lg = 0; lg < LC / 4; ++lg) {
    const float* nx = Up + (size_t)(lg * 4 + 4) * HH;  // tail prefetch lands in ws: harmless
    float v0 = nx[0], v1 = nx[HH], v2 = nx[2 * HH], v3 = nx[3 * HH];
    size_t o = (size_t)(lg * 4) * HH;
    float r0 = step(u0), r1 = step(u1), r2 = step(u2), r3 = step(u3);
    unsigned short h0 = f2bf(r0), h1 = f2bf(r1), h2 = f2bf(r2), h3 = f2bf(r3);
    Hh[o] = h0; Hh[o + HH] = h1; Hh[o + 2 * HH] = h2; Hh[o + 3 * HH] = h3;
    Hl[o]          = f2bf(r0 - bf2f(h0));
    Hl[o + HH]     = f2bf(r1 - bf2f(h1));
    Hl[o + 2 * HH] = f2bf(r2 - bf2f(h2));
    Hl[o + 3 * HH] = f2bf(r3 - bf2f(h3));
    u0 = v0; u1 = v1; u2 = v2; u3 = v3;
  }
}

// ---------------------------------------------------------------------------
extern "C" void kernel_launch(void* const* d_in, const int* in_sizes, int n_in,
                              void* d_out, int out_size, void* d_ws, size_t ws_size,
                              hipStream_t stream) {
  const int*   x      = (const int*)d_in[0];
  const float* emb    = (const float*)d_in[1];
  const float* Ws     = (const float*)d_in[2];
  const float* bs     = (const float*)d_in[3];
  const float* log_dt = (const float*)d_in[4];
  const float* lAr    = (const float*)d_in[5];
  const float* Aim    = (const float*)d_in[6];
  const float* Cre    = (const float*)d_in[7];
  const float* Cim    = (const float*)d_in[8];
  const float* Ds     = (const float*)d_in[9];
  const float* Wo     = (const float*)d_in[10];
  const float* bo     = (const float*)d_in[11];

  float*          bufU   = (float*)d_ws;                       // 67.1 MB
  unsigned short* bufAhi = (unsigned short*)(bufU + NELEM);    // 33.6 MB
  unsigned short* bufAlo = bufAhi + NELEM;                     // 33.6 MB
  float4*         par    = (float4*)(bufAlo + NELEM);          // 256 KB
  float2*         st     = (float2*)(par + HH * NN2);          // 31.5 MB
  unsigned short* wth    = (unsigned short*)(st + (size_t)BB * (NC - 1) * HH * NN2);  // 512 KB
  unsigned short* wtl    = wth + 512 * 512;                    // 512 KB

  k_embed<<<(int)(NELEM / 4 / 256), 256, 0, stream>>>(x, emb, bufAhi, bufAlo);
  for (int i = 0; i < NLAY; ++i) {
    k_params<<<HH * NN2 / 256, 256, 0, stream>>>(log_dt, lAr, Aim, Cre, Cim, i, par);
    k_trans<<<HH * 512 / 256, 256, 0, stream>>>(Ws + (size_t)i * HH * HH, HH, wth, wtl);
    k_gemm<1><<<dim3(HH / 128, BLM / 128), 256, 0, stream>>>(
        bufAhi, bufAlo, wth, wtl, bs + i * HH, bufU, HH);
    k_sa<<<dim3(2, NC - 1, BB), 256, 0, stream>>>(bufU, par, st);
    k_fold<<<BB * HH * NN2 / 256, 256, 0, stream>>>(par, st);
    k_sb<<<dim3(2, NC, BB), 256, 0, stream>>>(bufU, par, st, Ds + i * HH, bufAhi, bufAlo);
  }
  k_trans<<<OUTD * 512 / 256, 256, 0, stream>>>(Wo, OUTD, wth, wtl);
  k_gemm<0><<<dim3(OUTD / 128, BLM / 128), 256, 0, stream>>>(
      bufAhi, bufAlo, wth, wtl, bo, (float*)d_out, OUTD);
}

// Round 7
// 1108.490 us; speedup vs baseline: 2.8317x; 2.8317x over previous
//
#include <hip/hip_runtime.h>

#define BB 16
#define LL 2048
#define HH 512
#define NN2 32
#define NLAY 4
#define OUTD 256
#define BLM (BB*LL)                 // 32768 rows
#define NELEM ((size_t)BLM*HH)      // 16.78M activations
#define NC 16                       // SSM time chunks
#define LC (LL/NC)                  // 128
#define LGLC 7                      // log2(LC)

typedef __attribute__((ext_vector_type(8))) short s8v;   // 8 bf16 (4 VGPR)
typedef __attribute__((ext_vector_type(4))) float f4v;   // MFMA acc

__device__ __forceinline__ unsigned short f2bf(float f) {
  unsigned u = __float_as_uint(f);
  return (unsigned short)((u + 0x7fffu + ((u >> 16) & 1u)) >> 16);  // RNE
}
__device__ __forceinline__ float bf2f(unsigned short h) {
  return __uint_as_float((unsigned)h << 16);
}
__device__ __forceinline__ void gload16(const void* g, void* l) {
  __builtin_amdgcn_global_load_lds(
      (const __attribute__((address_space(1))) unsigned int*)g,
      (__attribute__((address_space(3))) unsigned int*)l, 16, 0, 0);
}

// ---------------- embedding gather -> bf16 hi/lo split ---------------------
__global__ __launch_bounds__(256) void k_embed(const int* __restrict__ x,
    const float* __restrict__ emb, unsigned short* __restrict__ Ahi,
    unsigned short* __restrict__ Alo) {
  int idx = blockIdx.x * 256 + threadIdx.x;      // one float4-group
  int j4 = idx & 127;
  int bl = idx >> 7;
  int tok = x[bl];
  float4 v = reinterpret_cast<const float4*>(emb)[tok * 128 + j4];
  unsigned short h0 = f2bf(v.x), h1 = f2bf(v.y), h2 = f2bf(v.z), h3 = f2bf(v.w);
  unsigned short l0 = f2bf(v.x - bf2f(h0)), l1 = f2bf(v.y - bf2f(h1));
  unsigned short l2 = f2bf(v.z - bf2f(h2)), l3 = f2bf(v.w - bf2f(h3));
  uint2 hp = make_uint2((unsigned)h0 | ((unsigned)h1 << 16),
                        (unsigned)h2 | ((unsigned)h3 << 16));
  uint2 lp = make_uint2((unsigned)l0 | ((unsigned)l1 << 16),
                        (unsigned)l2 | ((unsigned)l3 << 16));
  *reinterpret_cast<uint2*>(&Ahi[(size_t)idx * 4]) = hp;
  *reinterpret_cast<uint2*>(&Alo[(size_t)idx * 4]) = lp;
}

// ---------------- weight transpose + hi/lo split: Wt[n][k] = W[k][n] -------
__global__ __launch_bounds__(256) void k_trans(const float* __restrict__ W, int N,
    unsigned short* __restrict__ th, unsigned short* __restrict__ tl) {
  int t = blockIdx.x * 256 + threadIdx.x;        // over N*512, k fastest
  int k = t & 511, n = t >> 9;
  float v = W[(size_t)k * N + n];
  unsigned short hi = f2bf(v);
  th[(size_t)n * 512 + k] = hi;
  tl[(size_t)n * 512 + k] = f2bf(v - bf2f(hi));
}

// ---------------- per-layer SSM parameters; par laid out [n][h] ------------
__global__ __launch_bounds__(256) void k_params(const float* __restrict__ log_dt,
    const float* __restrict__ log_A_real, const float* __restrict__ A_imag,
    const float* __restrict__ C_re, const float* __restrict__ C_im,
    int layer, float4* __restrict__ par) {
  int idx = blockIdx.x * 256 + threadIdx.x;      // h*32+n
  int h = idx >> 5, n = idx & 31;
  int o = layer * HH * NN2 + idx;
  float dt  = expf(log_dt[layer * HH + h]);
  float Are = -expf(log_A_real[o]);
  float Aim = A_imag[o];
  float er = expf(Are * dt);
  float lr = er * cosf(Aim * dt), li = er * sinf(Aim * dt);
  float inv  = 1.0f / (Are * Are + Aim * Aim);
  float numr = lr - 1.0f, numi = li;
  float qr = (numr * Are + numi * Aim) * inv;
  float qi = (numi * Are - numr * Aim) * inv;
  float cr = C_re[o], ci = C_im[o];
  par[n * HH + h] = make_float4(lr, li, 2.0f * (cr * qr - ci * qi),
                                        2.0f * (cr * qi + ci * qr));
}

// ---------------- split-bf16 MFMA GEMM, 128x128 tile, BK=32, double-buffered
template<int EPI>
__global__ __launch_bounds__(256) void k_gemm(
    const unsigned short* __restrict__ Ahi, const unsigned short* __restrict__ Alo,
    const unsigned short* __restrict__ Bhi, const unsigned short* __restrict__ Blo,
    const float* __restrict__ bias, float* __restrict__ Out, int N) {
  __shared__ short lds[32768];                   // 64KB: 2 x (AH|AL|BH|BL)
  const int tid = threadIdx.x;
  const int lane = tid & 63, w = tid >> 6;
  const int wr = w >> 1, wc = w & 1;             // wave -> 64x64 quadrant
  const int m0 = blockIdx.y * 128, n0 = blockIdx.x * 128;
  const int lm = lane & 15, lk = lane >> 4;

  const unsigned short* ga[2][2]; const unsigned short* gb[2][2];
  short *da[2][2], *db[2][2];
#pragma unroll
  for (int f2 = 0; f2 < 2; ++f2) {
    int f = w * 2 + f2;                          // frag 0..7
    size_t ra = (size_t)(m0 + f * 16 + lm) * 512 + lk * 8;
    size_t rb = (size_t)(n0 + f * 16 + lm) * 512 + lk * 8;
    ga[0][f2] = Ahi + ra; ga[1][f2] = Alo + ra;
    gb[0][f2] = Bhi + rb; gb[1][f2] = Blo + rb;
    da[0][f2] = &lds[f * 512 + lane * 8];
    da[1][f2] = &lds[4096 + f * 512 + lane * 8];
    db[0][f2] = &lds[8192 + f * 512 + lane * 8];
    db[1][f2] = &lds[12288 + f * 512 + lane * 8];
  }
  f4v acc[4][4];
#pragma unroll
  for (int i = 0; i < 4; ++i)
#pragma unroll
    for (int j = 0; j < 4; ++j) acc[i][j] = (f4v){0.f, 0.f, 0.f, 0.f};

  auto stage = [&](int kt, int bofs) {
#pragma unroll
    for (int f2 = 0; f2 < 2; ++f2) {
      gload16(ga[0][f2] + kt * 32, da[0][f2] + bofs);
      gload16(ga[1][f2] + kt * 32, da[1][f2] + bofs);
      gload16(gb[0][f2] + kt * 32, db[0][f2] + bofs);
      gload16(gb[1][f2] + kt * 32, db[1][f2] + bofs);
    }
  };
  auto compute = [&](int bofs) {
    s8v ah[4], al[4], bh[4], bl[4];
#pragma unroll
    for (int i = 0; i < 4; ++i) {
      ah[i] = *(const s8v*)&lds[bofs + (wr * 4 + i) * 512 + lane * 8];
      al[i] = *(const s8v*)&lds[bofs + 4096 + (wr * 4 + i) * 512 + lane * 8];
      bh[i] = *(const s8v*)&lds[bofs + 8192 + (wc * 4 + i) * 512 + lane * 8];
      bl[i] = *(const s8v*)&lds[bofs + 12288 + (wc * 4 + i) * 512 + lane * 8];
    }
#pragma unroll
    for (int mi = 0; mi < 4; ++mi)
#pragma unroll
      for (int ni = 0; ni < 4; ++ni) {
        acc[mi][ni] = __builtin_amdgcn_mfma_f32_16x16x32_bf16(ah[mi], bh[ni], acc[mi][ni], 0, 0, 0);
        acc[mi][ni] = __builtin_amdgcn_mfma_f32_16x16x32_bf16(al[mi], bh[ni], acc[mi][ni], 0, 0, 0);
        acc[mi][ni] = __builtin_amdgcn_mfma_f32_16x16x32_bf16(ah[mi], bl[ni], acc[mi][ni], 0, 0, 0);
      }
  };

  stage(0, 0);
  __syncthreads();                               // tile 0 ready
#pragma unroll 1
  for (int t = 0; t < 8; ++t) {
    stage(2 * t + 1, 16384);                     // prefetch odd tile
    compute(0);                                  // compute even tile
    __syncthreads();                             // drains prefetch vmcnt
    if (t < 7) stage(2 * t + 2, 0);              // prefetch next even tile
    compute(16384);                              // compute odd tile
    __syncthreads();
  }
  // epilogue: C/D layout col=lane&15, row=(lane>>4)*4+reg
  float bb[4];
#pragma unroll
  for (int ni = 0; ni < 4; ++ni) bb[ni] = bias[n0 + wc * 64 + ni * 16 + lm];
#pragma unroll
  for (int mi = 0; mi < 4; ++mi) {
#pragma unroll
    for (int r = 0; r < 4; ++r) {
      int row = m0 + wr * 64 + mi * 16 + lk * 4 + r;
      float* po = Out + (size_t)row * N;
      const unsigned short* ph = Ahi + (size_t)row * 512;
      const unsigned short* pl = Alo + (size_t)row * 512;
#pragma unroll
      for (int ni = 0; ni < 4; ++ni) {
        int col = n0 + wc * 64 + ni * 16 + lm;
        float t = acc[mi][ni][r] + bb[ni];
        if (EPI) {
          t += bf2f(ph[col]) + bf2f(pl[col]);     // resid = hi+lo (err 2^-18)
          t = t < 0.f ? 2.f * t : 4.f * t;        // relu+res, x2
        }
        po[col] = t;
      }
    }
  }
}

// ---------------- SSM pass A: thread=(b,c,h,p), p owns 16 of 32 states -----
// 64 state regs -> no spill; u loads coalesced (lane pairs share h).
__global__ __launch_bounds__(256) void k_sa(const float* __restrict__ U,
    const float4* __restrict__ par, float2* __restrict__ st) {
  int tid = threadIdx.x;
  int p = tid & 1, hl = tid >> 1;                // 128 h per block
  int h = (blockIdx.x << 7) + hl;                // grid.x = 4
  int c = blockIdx.y, b = blockIdx.z;            // c in 0..NC-2
  float lr[16], li[16], gr[16], gi[16];
#pragma unroll
  for (int j = 0; j < 16; ++j) {
    float4 pp = par[(p * 16 + j) * HH + h];
    lr[j] = pp.x; li[j] = pp.y; gr[j] = 0.f; gi[j] = 0.f;
  }
  const float* Up = U + ((size_t)b * LL + (size_t)c * LC) * HH + h;
  auto step = [&](float uv) {
#pragma unroll
    for (int j = 0; j < 16; ++j) {
      float ngr = fmaf(lr[j], gr[j], fmaf(-li[j], gi[j], uv));
      gi[j] = fmaf(lr[j], gi[j], li[j] * gr[j]);
      gr[j] = ngr;
    }
  };
  float u0 = Up[0], u1 = Up[HH], u2 = Up[2 * HH], u3 = Up[3 * HH];
  for (int lg = 0; lg < LC / 4; ++lg) {
    const float* nx = Up + (size_t)(lg * 4 + 4) * HH;  // c<=NC-2: stays in U
    float v0 = nx[0], v1 = nx[HH], v2 = nx[2 * HH], v3 = nx[3 * HH];
    step(u0); step(u1); step(u2); step(u3);
    u0 = v0; u1 = v1; u2 = v2; u3 = v3;
  }
  size_t so = ((size_t)b * (NC - 1) + c) * (NN2 * HH) + (size_t)(p * 16) * HH + h;
#pragma unroll
  for (int j = 0; j < 16; ++j)
    st[so + (size_t)j * HH] = make_float2(gr[j], gi[j]);
}

// ---------------- fold: prefix-scan chunk states (in place, shifted) -------
// st layout [b][c][n][h]; after: slot c holds raw state at START of chunk c+1.
__global__ __launch_bounds__(256) void k_fold(const float4* __restrict__ par,
    float2* __restrict__ st) {
  int t = blockIdx.x * 256 + threadIdx.x;        // b*16384 + n*512 + h
  int r = t & 16383;
  int b = t >> 14;
  float4 p = par[r];                             // par is [n][h] -> index r
  float ar = p.x, ai = p.y;
#pragma unroll
  for (int s = 0; s < LGLC; ++s) { float nr = ar * ar - ai * ai; ai = 2.f * ar * ai; ar = nr; }  // lam^LC
  float gr = 0.f, gi = 0.f;
  size_t idx = (size_t)b * (NC - 1) * 16384 + r;
  for (int c = 0; c < NC - 1; ++c) {
    float2 s = st[idx + (size_t)c * 16384];
    float ngr = fmaf(ar, gr, fmaf(-ai, gi, s.x));
    gi = fmaf(ar, gi, fmaf(ai, gr, s.y));
    gr = ngr;
    st[idx + (size_t)c * 16384] = make_float2(gr, gi);
  }
}

// ---------------- SSM pass B: thread=(b,c,h,p), g-form, one shfl per step --
// g = lam*g + u; y = Sum (cr*gr - ci*gi); out = act2(y + (D+1)u) -> bf16 hi/lo
__global__ __launch_bounds__(256) void k_sb(const float* __restrict__ U,
    const float4* __restrict__ par, const float2* __restrict__ st,
    const float* __restrict__ D, unsigned short* __restrict__ Hhi,
    unsigned short* __restrict__ Hlo) {
  int tid = threadIdx.x;
  int p = tid & 1, hl = tid >> 1;                // 128 h per block
  int h = (blockIdx.x << 7) + hl;                // grid.x = 4
  int c = blockIdx.y, b = blockIdx.z;            // c in 0..NC-1
  float lr[16], li[16], cr[16], ci[16], gr[16], gi[16];
#pragma unroll
  for (int j = 0; j < 16; ++j) {
    float4 pp = par[(p * 16 + j) * HH + h];
    lr[j] = pp.x; li[j] = pp.y; cr[j] = pp.z; ci[j] = pp.w;
    gr[j] = 0.f; gi[j] = 0.f;
  }
  if (c > 0) {
    size_t so = ((size_t)b * (NC - 1) + (c - 1)) * (NN2 * HH) + (size_t)(p * 16) * HH + h;
#pragma unroll
    for (int j = 0; j < 16; ++j) {
      float2 s = st[so + (size_t)j * HH];
      gr[j] = s.x; gi[j] = s.y;
    }
  }
  float dp1 = D[h] + 1.0f;
  size_t base = ((size_t)b * LL + (size_t)c * LC) * HH + h;
  const float* Up = U + base;
  unsigned short* Hh = Hhi + base;
  unsigned short* Hl = Hlo + base;
  auto step = [&](float uv) -> float {
    float ya = 0.f, yb = 0.f, yc = 0.f, yd = 0.f;
#pragma unroll
    for (int j = 0; j < 16; ++j) {
      float ngr = fmaf(lr[j], gr[j], fmaf(-li[j], gi[j], uv));
      gi[j] = fmaf(lr[j], gi[j], li[j] * gr[j]);
      gr[j] = ngr;
      if (j & 1) { ya = fmaf(cr[j], gr[j], ya); yb = fmaf(ci[j], gi[j], yb); }
      else       { yc = fmaf(cr[j], gr[j], yc); yd = fmaf(ci[j], gi[j], yd); }
    }
    float ys = (ya + yc) - (yb + yd);
    ys += __shfl_xor(ys, 1);                     // partner lane has other 16 states
    float t4 = fmaf(dp1, uv, ys);
    return t4 < 0.f ? 2.f * t4 : 4.f * t4;
  };
  float u0 = Up[0], u1 = Up[HH], u2 = Up[2 * HH], u3 = Up[3 * HH];
  for (int lg = 0; lg < LC / 4; ++lg) {
    const float* nx = Up + (size_t)(lg * 4 + 4) * HH;  // tail prefetch lands in ws: harmless
    float v0 = nx[0], v1 = nx[HH], v2 = nx[2 * HH], v3 = nx[3 * HH];
    float r0 = step(u0), r1 = step(u1), r2 = step(u2), r3 = step(u3);
    // lane parity p stores steps 4lg+p and 4lg+2+p (both lanes hold all r's)
    size_t o = (size_t)(lg * 4) * HH;
    float ra = p ? r1 : r0;
    float rb = p ? r3 : r2;
    unsigned short ha = f2bf(ra), hb = f2bf(rb);
    Hh[o + (size_t)p * HH] = ha;
    Hh[o + (size_t)(2 + p) * HH] = hb;
    Hl[o + (size_t)p * HH] = f2bf(ra - bf2f(ha));
    Hl[o + (size_t)(2 + p) * HH] = f2bf(rb - bf2f(hb));
    u0 = v0; u1 = v1; u2 = v2; u3 = v3;
  }
}

// ---------------------------------------------------------------------------
extern "C" void kernel_launch(void* const* d_in, const int* in_sizes, int n_in,
                              void* d_out, int out_size, void* d_ws, size_t ws_size,
                              hipStream_t stream) {
  const int*   x      = (const int*)d_in[0];
  const float* emb    = (const float*)d_in[1];
  const float* Ws     = (const float*)d_in[2];
  const float* bs     = (const float*)d_in[3];
  const float* log_dt = (const float*)d_in[4];
  const float* lAr    = (const float*)d_in[5];
  const float* Aim    = (const float*)d_in[6];
  const float* Cre    = (const float*)d_in[7];
  const float* Cim    = (const float*)d_in[8];
  const float* Ds     = (const float*)d_in[9];
  const float* Wo     = (const float*)d_in[10];
  const float* bo     = (const float*)d_in[11];

  float*          bufU   = (float*)d_ws;                       // 67.1 MB
  unsigned short* bufAhi = (unsigned short*)(bufU + NELEM);    // 33.6 MB
  unsigned short* bufAlo = bufAhi + NELEM;                     // 33.6 MB
  float4*         par    = (float4*)(bufAlo + NELEM);          // 256 KB
  float2*         st     = (float2*)(par + HH * NN2);          // 31.5 MB
  unsigned short* wth    = (unsigned short*)(st + (size_t)BB * (NC - 1) * HH * NN2);  // 512 KB
  unsigned short* wtl    = wth + 512 * 512;                    // 512 KB

  k_embed<<<(int)(NELEM / 4 / 256), 256, 0, stream>>>(x, emb, bufAhi, bufAlo);
  for (int i = 0; i < NLAY; ++i) {
    k_params<<<HH * NN2 / 256, 256, 0, stream>>>(log_dt, lAr, Aim, Cre, Cim, i, par);
    k_trans<<<HH * 512 / 256, 256, 0, stream>>>(Ws + (size_t)i * HH * HH, HH, wth, wtl);
    k_gemm<1><<<dim3(HH / 128, BLM / 128), 256, 0, stream>>>(
        bufAhi, bufAlo, wth, wtl, bs + i * HH, bufU, HH);
    k_sa<<<dim3(4, NC - 1, BB), 256, 0, stream>>>(bufU, par, st);
    k_fold<<<BB * HH * NN2 / 256, 256, 0, stream>>>(par, st);
    k_sb<<<dim3(4, NC, BB), 256, 0, stream>>>(bufU, par, st, Ds + i * HH, bufAhi, bufAlo);
  }
  k_trans<<<OUTD * 512 / 256, 256, 0, stream>>>(Wo, OUTD, wth, wtl);
  k_gemm<0><<<dim3(OUTD / 128, BLM / 128), 256, 0, stream>>>(
      bufAhi, bufAlo, wth, wtl, bo, (float*)d_out, OUTD);
}

// Round 8
// 1099.808 us; speedup vs baseline: 2.8540x; 1.0079x over previous
//
#include <hip/hip_runtime.h>

#define BB 16
#define LL 2048
#define HH 512
#define NN2 32
#define NLAY 4
#define OUTD 256
#define BLM (BB*LL)                 // 32768 rows
#define NELEM ((size_t)BLM*HH)      // 16.78M activations
#define NC 16                       // SSM time chunks
#define LC (LL/NC)                  // 128
#define LGLC 7                      // log2(LC)

typedef __attribute__((ext_vector_type(8))) short s8v;   // 8 bf16 (4 VGPR)
typedef __attribute__((ext_vector_type(4))) float f4v;   // MFMA acc

__device__ __forceinline__ unsigned short f2bf(float f) {
  unsigned u = __float_as_uint(f);
  return (unsigned short)((u + 0x7fffu + ((u >> 16) & 1u)) >> 16);  // RNE
}
__device__ __forceinline__ float bf2f(unsigned short h) {
  return __uint_as_float((unsigned)h << 16);
}
__device__ __forceinline__ void gload16(const void* g, void* l) {
  __builtin_amdgcn_global_load_lds(
      (const __attribute__((address_space(1))) unsigned int*)g,
      (__attribute__((address_space(3))) unsigned int*)l, 16, 0, 0);
}
// pair-sum via DPP quad_perm [1,0,3,2] — VALU only, replaces ds_bpermute
__device__ __forceinline__ float pairsum(float x) {
  int p = __builtin_amdgcn_update_dpp(0, __float_as_int(x), 0xB1, 0xF, 0xF, true);
  return x + __int_as_float(p);
}

// ---------------- embedding gather -> bf16 hi/lo split ---------------------
__global__ __launch_bounds__(256) void k_embed(const int* __restrict__ x,
    const float* __restrict__ emb, unsigned short* __restrict__ Ahi,
    unsigned short* __restrict__ Alo) {
  int idx = blockIdx.x * 256 + threadIdx.x;      // one float4-group
  int j4 = idx & 127;
  int bl = idx >> 7;
  int tok = x[bl];
  float4 v = reinterpret_cast<const float4*>(emb)[tok * 128 + j4];
  unsigned short h0 = f2bf(v.x), h1 = f2bf(v.y), h2 = f2bf(v.z), h3 = f2bf(v.w);
  unsigned short l0 = f2bf(v.x - bf2f(h0)), l1 = f2bf(v.y - bf2f(h1));
  unsigned short l2 = f2bf(v.z - bf2f(h2)), l3 = f2bf(v.w - bf2f(h3));
  uint2 hp = make_uint2((unsigned)h0 | ((unsigned)h1 << 16),
                        (unsigned)h2 | ((unsigned)h3 << 16));
  uint2 lp = make_uint2((unsigned)l0 | ((unsigned)l1 << 16),
                        (unsigned)l2 | ((unsigned)l3 << 16));
  *reinterpret_cast<uint2*>(&Ahi[(size_t)idx * 4]) = hp;
  *reinterpret_cast<uint2*>(&Alo[(size_t)idx * 4]) = lp;
}

// ---------------- weight transpose + hi/lo split: Wt[n][k] = W[k][n] -------
__global__ __launch_bounds__(256) void k_trans(const float* __restrict__ W, int N,
    unsigned short* __restrict__ th, unsigned short* __restrict__ tl) {
  int t = blockIdx.x * 256 + threadIdx.x;        // over N*512, k fastest
  int k = t & 511, n = t >> 9;
  float v = W[(size_t)k * N + n];
  unsigned short hi = f2bf(v);
  th[(size_t)n * 512 + k] = hi;
  tl[(size_t)n * 512 + k] = f2bf(v - bf2f(hi));
}

// ---------------- per-layer SSM parameters; par laid out [n][h] ------------
__global__ __launch_bounds__(256) void k_params(const float* __restrict__ log_dt,
    const float* __restrict__ log_A_real, const float* __restrict__ A_imag,
    const float* __restrict__ C_re, const float* __restrict__ C_im,
    int layer, float4* __restrict__ par) {
  int idx = blockIdx.x * 256 + threadIdx.x;      // h*32+n
  int h = idx >> 5, n = idx & 31;
  int o = layer * HH * NN2 + idx;
  float dt  = expf(log_dt[layer * HH + h]);
  float Are = -expf(log_A_real[o]);
  float Aim = A_imag[o];
  float er = expf(Are * dt);
  float lr = er * cosf(Aim * dt), li = er * sinf(Aim * dt);
  float inv  = 1.0f / (Are * Are + Aim * Aim);
  float numr = lr - 1.0f, numi = li;
  float qr = (numr * Are + numi * Aim) * inv;
  float qi = (numi * Are - numr * Aim) * inv;
  float cr = C_re[o], ci = C_im[o];
  par[n * HH + h] = make_float4(lr, li, 2.0f * (cr * qr - ci * qi),
                                        2.0f * (cr * qi + ci * qr));
}

// ---------------- split-bf16 MFMA GEMM, 128x128 tile, BK=32 ----------------
// Pipelined with counted vmcnt: stage(kt+1) -> vmcnt(8) -> barrier ->
// compute(kt) -> barrier. Tile kt+1's 8 loads/wave stay in flight across the
// barriers (raw asm barriers; no compiler vmcnt(0) drain). XCD-swizzled grid.
template<int EPI>
__global__ __launch_bounds__(256) void k_gemm(
    const unsigned short* __restrict__ Ahi, const unsigned short* __restrict__ Alo,
    const unsigned short* __restrict__ Bhi, const unsigned short* __restrict__ Blo,
    const float* __restrict__ bias, float* __restrict__ Out, int N) {
  __shared__ short lds[32768];                   // 64KB: 2 x (AH|AL|BH|BL)
  const int tid = threadIdx.x;
  const int lane = tid & 63, w = tid >> 6;
  const int wr = w >> 1, wc = w & 1;             // wave -> 64x64 quadrant
  // bijective XCD swizzle: consecutive new-ids (sharing an A-panel) land on
  // one XCD -> A-panel L2 reuse. nwg % 8 == 0 for both GEMMs.
  const int nwg = gridDim.x * gridDim.y;
  const int lin = blockIdx.y * gridDim.x + blockIdx.x;
  const int cpx = nwg >> 3;
  const int nid = (lin & 7) * cpx + (lin >> 3);
  const int bx = nid & (gridDim.x - 1), by = nid / gridDim.x;
  const int m0 = by * 128, n0 = bx * 128;
  const int lm = lane & 15, lk = lane >> 4;

  const unsigned short* ga[2][2]; const unsigned short* gb[2][2];
  short *da[2][2], *db[2][2];
#pragma unroll
  for (int f2 = 0; f2 < 2; ++f2) {
    int f = w * 2 + f2;                          // frag 0..7
    size_t ra = (size_t)(m0 + f * 16 + lm) * 512 + lk * 8;
    size_t rb = (size_t)(n0 + f * 16 + lm) * 512 + lk * 8;
    ga[0][f2] = Ahi + ra; ga[1][f2] = Alo + ra;
    gb[0][f2] = Bhi + rb; gb[1][f2] = Blo + rb;
    da[0][f2] = &lds[f * 512 + lane * 8];
    da[1][f2] = &lds[4096 + f * 512 + lane * 8];
    db[0][f2] = &lds[8192 + f * 512 + lane * 8];
    db[1][f2] = &lds[12288 + f * 512 + lane * 8];
  }
  f4v acc[4][4];
#pragma unroll
  for (int i = 0; i < 4; ++i)
#pragma unroll
    for (int j = 0; j < 4; ++j) acc[i][j] = (f4v){0.f, 0.f, 0.f, 0.f};

  auto stage = [&](int kt, int bofs) {           // 8 gload16 per lane
#pragma unroll
    for (int f2 = 0; f2 < 2; ++f2) {
      gload16(ga[0][f2] + kt * 32, da[0][f2] + bofs);
      gload16(ga[1][f2] + kt * 32, da[1][f2] + bofs);
      gload16(gb[0][f2] + kt * 32, db[0][f2] + bofs);
      gload16(gb[1][f2] + kt * 32, db[1][f2] + bofs);
    }
  };
  auto compute = [&](int bofs) {
    s8v ah[4], al[4], bh[4], bl[4];
#pragma unroll
    for (int i = 0; i < 4; ++i) {
      ah[i] = *(const s8v*)&lds[bofs + (wr * 4 + i) * 512 + lane * 8];
      al[i] = *(const s8v*)&lds[bofs + 4096 + (wr * 4 + i) * 512 + lane * 8];
      bh[i] = *(const s8v*)&lds[bofs + 8192 + (wc * 4 + i) * 512 + lane * 8];
      bl[i] = *(const s8v*)&lds[bofs + 12288 + (wc * 4 + i) * 512 + lane * 8];
    }
#pragma unroll
    for (int mi = 0; mi < 4; ++mi)
#pragma unroll
      for (int ni = 0; ni < 4; ++ni) {
        acc[mi][ni] = __builtin_amdgcn_mfma_f32_16x16x32_bf16(ah[mi], bh[ni], acc[mi][ni], 0, 0, 0);
        acc[mi][ni] = __builtin_amdgcn_mfma_f32_16x16x32_bf16(al[mi], bh[ni], acc[mi][ni], 0, 0, 0);
        acc[mi][ni] = __builtin_amdgcn_mfma_f32_16x16x32_bf16(ah[mi], bl[ni], acc[mi][ni], 0, 0, 0);
      }
  };

  stage(0, 0);
#pragma unroll 1
  for (int kt = 0; kt < 15; ++kt) {
    stage(kt + 1, ((kt + 1) & 1) << 14);         // prefetch next tile
    asm volatile("s_waitcnt vmcnt(8)" ::: "memory");   // tile kt done; kt+1 flying
    asm volatile("s_barrier" ::: "memory");            // all waves' kt in LDS
    compute((kt & 1) << 14);
    asm volatile("s_barrier" ::: "memory");            // kt-buffer free for reuse
  }
  asm volatile("s_waitcnt vmcnt(0)" ::: "memory");
  asm volatile("s_barrier" ::: "memory");
  compute(16384);                                // tile 15 (odd buffer)

  // epilogue: C/D layout col=lane&15, row=(lane>>4)*4+reg
  float bb[4];
#pragma unroll
  for (int ni = 0; ni < 4; ++ni) bb[ni] = bias[n0 + wc * 64 + ni * 16 + lm];
#pragma unroll
  for (int mi = 0; mi < 4; ++mi) {
#pragma unroll
    for (int r = 0; r < 4; ++r) {
      int row = m0 + wr * 64 + mi * 16 + lk * 4 + r;
      float* po = Out + (size_t)row * N;
      const unsigned short* ph = Ahi + (size_t)row * 512;
      const unsigned short* pl = Alo + (size_t)row * 512;
#pragma unroll
      for (int ni = 0; ni < 4; ++ni) {
        int col = n0 + wc * 64 + ni * 16 + lm;
        float t = acc[mi][ni][r] + bb[ni];
        if (EPI) {
          t += bf2f(ph[col]) + bf2f(pl[col]);     // resid = hi+lo (err 2^-18)
          t = t < 0.f ? 2.f * t : 4.f * t;        // relu+res, x2
        }
        po[col] = t;
      }
    }
  }
}

// ---------------- SSM pass A: thread=(b,c,h,p), p owns 16 of 32 states -----
// 64 state regs -> no spill; u loads coalesced; prefetch depth 8.
__global__ __launch_bounds__(256) void k_sa(const float* __restrict__ U,
    const float4* __restrict__ par, float2* __restrict__ st) {
  int tid = threadIdx.x;
  int p = tid & 1, hl = tid >> 1;                // 128 h per block
  int h = (blockIdx.x << 7) + hl;                // grid.x = 4
  int c = blockIdx.y, b = blockIdx.z;            // c in 0..NC-2
  float lr[16], li[16], gr[16], gi[16];
#pragma unroll
  for (int j = 0; j < 16; ++j) {
    float4 pp = par[(p * 16 + j) * HH + h];
    lr[j] = pp.x; li[j] = pp.y; gr[j] = 0.f; gi[j] = 0.f;
  }
  const float* Up = U + ((size_t)b * LL + (size_t)c * LC) * HH + h;
  auto step = [&](float uv) {
#pragma unroll
    for (int j = 0; j < 16; ++j) {
      float ngr = fmaf(lr[j], gr[j], fmaf(-li[j], gi[j], uv));
      gi[j] = fmaf(lr[j], gi[j], li[j] * gr[j]);
      gr[j] = ngr;
    }
  };
  float u0 = Up[0], u1 = Up[HH], u2 = Up[2 * HH], u3 = Up[3 * HH];
  float u4 = Up[4 * HH], u5 = Up[5 * HH], u6 = Up[6 * HH], u7 = Up[7 * HH];
  for (int lg = 0; lg < LC / 4; ++lg) {
    const float* nx = Up + (size_t)(lg * 4 + 8) * HH;  // tail lands in ws: harmless
    float v0 = nx[0], v1 = nx[HH], v2 = nx[2 * HH], v3 = nx[3 * HH];
    step(u0); step(u1); step(u2); step(u3);
    u0 = u4; u1 = u5; u2 = u6; u3 = u7;
    u4 = v0; u5 = v1; u6 = v2; u7 = v3;
  }
  size_t so = ((size_t)b * (NC - 1) + c) * (NN2 * HH) + (size_t)(p * 16) * HH + h;
#pragma unroll
  for (int j = 0; j < 16; ++j)
    st[so + (size_t)j * HH] = make_float2(gr[j], gi[j]);
}

// ---------------- fold: prefix-scan chunk states (in place, shifted) -------
// st layout [b][c][n][h]; after: slot c holds raw state at START of chunk c+1.
__global__ __launch_bounds__(256) void k_fold(const float4* __restrict__ par,
    float2* __restrict__ st) {
  int t = blockIdx.x * 256 + threadIdx.x;        // b*16384 + n*512 + h
  int r = t & 16383;
  int b = t >> 14;
  float4 p = par[r];                             // par is [n][h] -> index r
  float ar = p.x, ai = p.y;
#pragma unroll
  for (int s = 0; s < LGLC; ++s) { float nr = ar * ar - ai * ai; ai = 2.f * ar * ai; ar = nr; }  // lam^LC
  float gr = 0.f, gi = 0.f;
  size_t idx = (size_t)b * (NC - 1) * 16384 + r;
  for (int c = 0; c < NC - 1; ++c) {
    float2 s = st[idx + (size_t)c * 16384];
    float ngr = fmaf(ar, gr, fmaf(-ai, gi, s.x));
    gi = fmaf(ar, gi, fmaf(ai, gr, s.y));
    gr = ngr;
    st[idx + (size_t)c * 16384] = make_float2(gr, gi);
  }
}

// ---------------- SSM pass B: thread=(b,c,h,p), g-form, DPP pair-sum -------
// g = lam*g + u; y = Sum (cr*gr - ci*gi); out = act2(y + (D+1)u) -> bf16 hi/lo
__global__ __launch_bounds__(256) void k_sb(const float* __restrict__ U,
    const float4* __restrict__ par, const float2* __restrict__ st,
    const float* __restrict__ D, unsigned short* __restrict__ Hhi,
    unsigned short* __restrict__ Hlo) {
  int tid = threadIdx.x;
  int p = tid & 1, hl = tid >> 1;                // 128 h per block
  int h = (blockIdx.x << 7) + hl;                // grid.x = 4
  int c = blockIdx.y, b = blockIdx.z;            // c in 0..NC-1
  float lr[16], li[16], cr[16], ci[16], gr[16], gi[16];
#pragma unroll
  for (int j = 0; j < 16; ++j) {
    float4 pp = par[(p * 16 + j) * HH + h];
    lr[j] = pp.x; li[j] = pp.y; cr[j] = pp.z; ci[j] = pp.w;
    gr[j] = 0.f; gi[j] = 0.f;
  }
  if (c > 0) {
    size_t so = ((size_t)b * (NC - 1) + (c - 1)) * (NN2 * HH) + (size_t)(p * 16) * HH + h;
#pragma unroll
    for (int j = 0; j < 16; ++j) {
      float2 s = st[so + (size_t)j * HH];
      gr[j] = s.x; gi[j] = s.y;
    }
  }
  float dp1 = D[h] + 1.0f;
  size_t base = ((size_t)b * LL + (size_t)c * LC) * HH + h;
  const float* Up = U + base;
  unsigned short* Hh = Hhi + base;
  unsigned short* Hl = Hlo + base;
  auto step = [&](float uv) -> float {
    float ya = 0.f, yb = 0.f, yc = 0.f, yd = 0.f;
#pragma unroll
    for (int j = 0; j < 16; ++j) {
      float ngr = fmaf(lr[j], gr[j], fmaf(-li[j], gi[j], uv));
      gi[j] = fmaf(lr[j], gi[j], li[j] * gr[j]);
      gr[j] = ngr;
      if (j & 1) { ya = fmaf(cr[j], gr[j], ya); yb = fmaf(ci[j], gi[j], yb); }
      else       { yc = fmaf(cr[j], gr[j], yc); yd = fmaf(ci[j], gi[j], yd); }
    }
    float ys = pairsum((ya + yc) - (yb + yd));   // partner lane: other 16 states
    float t4 = fmaf(dp1, uv, ys);
    return t4 < 0.f ? 2.f * t4 : 4.f * t4;
  };
  float u0 = Up[0], u1 = Up[HH], u2 = Up[2 * HH], u3 = Up[3 * HH];
  float u4 = Up[4 * HH], u5 = Up[5 * HH], u6 = Up[6 * HH], u7 = Up[7 * HH];
  for (int lg = 0; lg < LC / 4; ++lg) {
    const float* nx = Up + (size_t)(lg * 4 + 8) * HH;  // tail lands in ws: harmless
    float v0 = nx[0], v1 = nx[HH], v2 = nx[2 * HH], v3 = nx[3 * HH];
    float r0 = step(u0), r1 = step(u1), r2 = step(u2), r3 = step(u3);
    // lane parity p stores steps 4lg+p and 4lg+2+p (both lanes hold all r's)
    size_t o = (size_t)(lg * 4) * HH;
    float ra = p ? r1 : r0;
    float rb = p ? r3 : r2;
    unsigned short ha = f2bf(ra), hb = f2bf(rb);
    Hh[o + (size_t)p * HH] = ha;
    Hh[o + (size_t)(2 + p) * HH] = hb;
    Hl[o + (size_t)p * HH] = f2bf(ra - bf2f(ha));
    Hl[o + (size_t)(2 + p) * HH] = f2bf(rb - bf2f(hb));
    u0 = u4; u1 = u5; u2 = u6; u3 = u7;
    u4 = v0; u5 = v1; u6 = v2; u7 = v3;
  }
}

// ---------------------------------------------------------------------------
extern "C" void kernel_launch(void* const* d_in, const int* in_sizes, int n_in,
                              void* d_out, int out_size, void* d_ws, size_t ws_size,
                              hipStream_t stream) {
  const int*   x      = (const int*)d_in[0];
  const float* emb    = (const float*)d_in[1];
  const float* Ws     = (const float*)d_in[2];
  const float* bs     = (const float*)d_in[3];
  const float* log_dt = (const float*)d_in[4];
  const float* lAr    = (const float*)d_in[5];
  const float* Aim    = (const float*)d_in[6];
  const float* Cre    = (const float*)d_in[7];
  const float* Cim    = (const float*)d_in[8];
  const float* Ds     = (const float*)d_in[9];
  const float* Wo     = (const float*)d_in[10];
  const float* bo     = (const float*)d_in[11];

  float*          bufU   = (float*)d_ws;                       // 67.1 MB
  unsigned short* bufAhi = (unsigned short*)(bufU + NELEM);    // 33.6 MB
  unsigned short* bufAlo = bufAhi + NELEM;                     // 33.6 MB
  float4*         par    = (float4*)(bufAlo + NELEM);          // 256 KB
  float2*         st     = (float2*)(par + HH * NN2);          // 31.5 MB
  unsigned short* wth    = (unsigned short*)(st + (size_t)BB * (NC - 1) * HH * NN2);  // 512 KB
  unsigned short* wtl    = wth + 512 * 512;                    // 512 KB

  k_embed<<<(int)(NELEM / 4 / 256), 256, 0, stream>>>(x, emb, bufAhi, bufAlo);
  for (int i = 0; i < NLAY; ++i) {
    k_params<<<HH * NN2 / 256, 256, 0, stream>>>(log_dt, lAr, Aim, Cre, Cim, i, par);
    k_trans<<<HH * 512 / 256, 256, 0, stream>>>(Ws + (size_t)i * HH * HH, HH, wth, wtl);
    k_gemm<1><<<dim3(HH / 128, BLM / 128), 256, 0, stream>>>(
        bufAhi, bufAlo, wth, wtl, bs + i * HH, bufU, HH);
    k_sa<<<dim3(4, NC - 1, BB), 256, 0, stream>>>(bufU, par, st);
    k_fold<<<BB * HH * NN2 / 256, 256, 0, stream>>>(par, st);
    k_sb<<<dim3(4, NC, BB), 256, 0, stream>>>(bufU, par, st, Ds + i * HH, bufAhi, bufAlo);
  }
  k_trans<<<OUTD * 512 / 256, 256, 0, stream>>>(Wo, OUTD, wth, wtl);
  k_gemm<0><<<dim3(OUTD / 128, BLM / 128), 256, 0, stream>>>(
      bufAhi, bufAlo, wth, wtl, bo, (float*)d_out, OUTD);
}

// Round 9
// 1042.393 us; speedup vs baseline: 3.0112x; 1.0551x over previous
//
#include <hip/hip_runtime.h>

#define BB 16
#define LL 2048
#define HH 512
#define NN2 32
#define NLAY 4
#define OUTD 256
#define BLM (BB*LL)                 // 32768 rows
#define NELEM ((size_t)BLM*HH)      // 16.78M activations
#define NC 16                       // SSM time chunks
#define LC (LL/NC)                  // 128
#define LGLC 7                      // log2(LC)

typedef __attribute__((ext_vector_type(8))) short s8v;   // 8 bf16 (4 VGPR)
typedef __attribute__((ext_vector_type(4))) float f4v;   // MFMA acc

__device__ __forceinline__ unsigned short f2bf(float f) {
  unsigned u = __float_as_uint(f);
  return (unsigned short)((u + 0x7fffu + ((u >> 16) & 1u)) >> 16);  // RNE
}
__device__ __forceinline__ float bf2f(unsigned short h) {
  return __uint_as_float((unsigned)h << 16);
}
__device__ __forceinline__ void gload16(const void* g, void* l) {
  __builtin_amdgcn_global_load_lds(
      (const __attribute__((address_space(1))) unsigned int*)g,
      (__attribute__((address_space(3))) unsigned int*)l, 16, 0, 0);
}
// pair-sum via DPP quad_perm [1,0,3,2] — VALU only, replaces ds_bpermute
__device__ __forceinline__ float pairsum(float x) {
  int p = __builtin_amdgcn_update_dpp(0, __float_as_int(x), 0xB1, 0xF, 0xF, true);
  return x + __int_as_float(p);
}

// ---------------- embedding gather -> bf16 hi/lo split ---------------------
__global__ __launch_bounds__(256) void k_embed(const int* __restrict__ x,
    const float* __restrict__ emb, unsigned short* __restrict__ Ahi,
    unsigned short* __restrict__ Alo) {
  int idx = blockIdx.x * 256 + threadIdx.x;      // one float4-group
  int j4 = idx & 127;
  int bl = idx >> 7;
  int tok = x[bl];
  float4 v = reinterpret_cast<const float4*>(emb)[tok * 128 + j4];
  unsigned short h0 = f2bf(v.x), h1 = f2bf(v.y), h2 = f2bf(v.z), h3 = f2bf(v.w);
  unsigned short l0 = f2bf(v.x - bf2f(h0)), l1 = f2bf(v.y - bf2f(h1));
  unsigned short l2 = f2bf(v.z - bf2f(h2)), l3 = f2bf(v.w - bf2f(h3));
  uint2 hp = make_uint2((unsigned)h0 | ((unsigned)h1 << 16),
                        (unsigned)h2 | ((unsigned)h3 << 16));
  uint2 lp = make_uint2((unsigned)l0 | ((unsigned)l1 << 16),
                        (unsigned)l2 | ((unsigned)l3 << 16));
  *reinterpret_cast<uint2*>(&Ahi[(size_t)idx * 4]) = hp;
  *reinterpret_cast<uint2*>(&Alo[(size_t)idx * 4]) = lp;
}

// ------- weight transpose + hi/lo split: Wt[n][k] = W[k][n] (+ I) ----------
// addI folds the residual into the weights: A@(W+I)+b == A@W+b+A.
__global__ __launch_bounds__(256) void k_trans(const float* __restrict__ W, int N,
    unsigned short* __restrict__ th, unsigned short* __restrict__ tl, int addI) {
  int t = blockIdx.x * 256 + threadIdx.x;        // over N*512, k fastest
  int k = t & 511, n = t >> 9;
  float v = W[(size_t)k * N + n] + ((addI && k == n) ? 1.0f : 0.0f);
  unsigned short hi = f2bf(v);
  th[(size_t)n * 512 + k] = hi;
  tl[(size_t)n * 512 + k] = f2bf(v - bf2f(hi));
}

// ---------------- per-layer SSM parameters; par laid out [n][h] ------------
__global__ __launch_bounds__(256) void k_params(const float* __restrict__ log_dt,
    const float* __restrict__ log_A_real, const float* __restrict__ A_imag,
    const float* __restrict__ C_re, const float* __restrict__ C_im,
    int layer, float4* __restrict__ par) {
  int idx = blockIdx.x * 256 + threadIdx.x;      // h*32+n
  int h = idx >> 5, n = idx & 31;
  int o = layer * HH * NN2 + idx;
  float dt  = expf(log_dt[layer * HH + h]);
  float Are = -expf(log_A_real[o]);
  float Aim = A_imag[o];
  float er = expf(Are * dt);
  float lr = er * cosf(Aim * dt), li = er * sinf(Aim * dt);
  float inv  = 1.0f / (Are * Are + Aim * Aim);
  float numr = lr - 1.0f, numi = li;
  float qr = (numr * Are + numi * Aim) * inv;
  float qi = (numi * Are - numr * Aim) * inv;
  float cr = C_re[o], ci = C_im[o];
  par[n * HH + h] = make_float4(lr, li, 2.0f * (cr * qr - ci * qi),
                                        2.0f * (cr * qi + ci * qr));
}

// ---------------- split-bf16 MFMA GEMM, 128x128 tile, BK=32 ----------------
// Pipelined with counted vmcnt: stage(kt+1) -> vmcnt(8) -> barrier ->
// compute(kt) -> barrier. Residual folded into W (addI) so no A re-read.
// Dispatch remap: the 4 (2) N-blocks sharing an A-panel land on the SAME XCD
// within 32 consecutive dispatch ids -> A-panel read once from HBM, L2-hit
// for the rest. XCD = d%8 (HW round-robin).
template<int EPI>
__global__ __launch_bounds__(256) void k_gemm(
    const unsigned short* __restrict__ Ahi, const unsigned short* __restrict__ Alo,
    const unsigned short* __restrict__ Bhi, const unsigned short* __restrict__ Blo,
    const float* __restrict__ bias, float* __restrict__ Out, int N) {
  __shared__ short lds[32768];                   // 64KB: 2 x (AH|AL|BH|BL)
  const int tid = threadIdx.x;
  const int lane = tid & 63, w = tid >> 6;
  const int wr = w >> 1, wc = w & 1;             // wave -> 64x64 quadrant
  const int d = blockIdx.y * gridDim.x + blockIdx.x;   // HW dispatch id
  const int xcd = d & 7, s = (d >> 3) & 3, q = d >> 5;
  int bx, by;
  if (gridDim.x == 4) { bx = s;     by = q * 8  + xcd; }
  else                { bx = s & 1; by = q * 16 + xcd * 2 + (s >> 1); }
  const int m0 = by * 128, n0 = bx * 128;
  const int lm = lane & 15, lk = lane >> 4;

  const unsigned short* ga[2][2]; const unsigned short* gb[2][2];
  short *da[2][2], *db[2][2];
#pragma unroll
  for (int f2 = 0; f2 < 2; ++f2) {
    int f = w * 2 + f2;                          // frag 0..7
    size_t ra = (size_t)(m0 + f * 16 + lm) * 512 + lk * 8;
    size_t rb = (size_t)(n0 + f * 16 + lm) * 512 + lk * 8;
    ga[0][f2] = Ahi + ra; ga[1][f2] = Alo + ra;
    gb[0][f2] = Bhi + rb; gb[1][f2] = Blo + rb;
    da[0][f2] = &lds[f * 512 + lane * 8];
    da[1][f2] = &lds[4096 + f * 512 + lane * 8];
    db[0][f2] = &lds[8192 + f * 512 + lane * 8];
    db[1][f2] = &lds[12288 + f * 512 + lane * 8];
  }
  f4v acc[4][4];
#pragma unroll
  for (int i = 0; i < 4; ++i)
#pragma unroll
    for (int j = 0; j < 4; ++j) acc[i][j] = (f4v){0.f, 0.f, 0.f, 0.f};

  auto stage = [&](int kt, int bofs) {           // 8 gload16 per lane
#pragma unroll
    for (int f2 = 0; f2 < 2; ++f2) {
      gload16(ga[0][f2] + kt * 32, da[0][f2] + bofs);
      gload16(ga[1][f2] + kt * 32, da[1][f2] + bofs);
      gload16(gb[0][f2] + kt * 32, db[0][f2] + bofs);
      gload16(gb[1][f2] + kt * 32, db[1][f2] + bofs);
    }
  };
  auto compute = [&](int bofs) {
    s8v ah[4], al[4], bh[4], bl[4];
#pragma unroll
    for (int i = 0; i < 4; ++i) {
      ah[i] = *(const s8v*)&lds[bofs + (wr * 4 + i) * 512 + lane * 8];
      al[i] = *(const s8v*)&lds[bofs + 4096 + (wr * 4 + i) * 512 + lane * 8];
      bh[i] = *(const s8v*)&lds[bofs + 8192 + (wc * 4 + i) * 512 + lane * 8];
      bl[i] = *(const s8v*)&lds[bofs + 12288 + (wc * 4 + i) * 512 + lane * 8];
    }
#pragma unroll
    for (int mi = 0; mi < 4; ++mi)
#pragma unroll
      for (int ni = 0; ni < 4; ++ni) {
        acc[mi][ni] = __builtin_amdgcn_mfma_f32_16x16x32_bf16(ah[mi], bh[ni], acc[mi][ni], 0, 0, 0);
        acc[mi][ni] = __builtin_amdgcn_mfma_f32_16x16x32_bf16(al[mi], bh[ni], acc[mi][ni], 0, 0, 0);
        acc[mi][ni] = __builtin_amdgcn_mfma_f32_16x16x32_bf16(ah[mi], bl[ni], acc[mi][ni], 0, 0, 0);
      }
  };

  stage(0, 0);
#pragma unroll 1
  for (int kt = 0; kt < 15; ++kt) {
    stage(kt + 1, ((kt + 1) & 1) << 14);         // prefetch next tile
    asm volatile("s_waitcnt vmcnt(8)" ::: "memory");   // tile kt done; kt+1 flying
    asm volatile("s_barrier" ::: "memory");            // all waves' kt in LDS
    compute((kt & 1) << 14);
    asm volatile("s_barrier" ::: "memory");            // kt-buffer free for reuse
  }
  asm volatile("s_waitcnt vmcnt(0)" ::: "memory");
  asm volatile("s_barrier" ::: "memory");
  compute(16384);                                // tile 15 (odd buffer)

  // epilogue: C/D layout col=lane&15, row=(lane>>4)*4+reg; resid is in W+I
  float bb[4];
#pragma unroll
  for (int ni = 0; ni < 4; ++ni) bb[ni] = bias[n0 + wc * 64 + ni * 16 + lm];
#pragma unroll
  for (int mi = 0; mi < 4; ++mi) {
#pragma unroll
    for (int r = 0; r < 4; ++r) {
      int row = m0 + wr * 64 + mi * 16 + lk * 4 + r;
      float* po = Out + (size_t)row * N;
#pragma unroll
      for (int ni = 0; ni < 4; ++ni) {
        int col = n0 + wc * 64 + ni * 16 + lm;
        float t = acc[mi][ni][r] + bb[ni];
        if (EPI) t = t < 0.f ? 2.f * t : 4.f * t;   // relu+res, x2
        po[col] = t;
      }
    }
  }
}

// ---------------- SSM pass A: thread=(b,c,h,p), p owns 16 of 32 states -----
// 64 state regs -> no spill; u loads coalesced; prefetch depth 8.
__global__ __launch_bounds__(256) void k_sa(const float* __restrict__ U,
    const float4* __restrict__ par, float2* __restrict__ st) {
  int tid = threadIdx.x;
  int p = tid & 1, hl = tid >> 1;                // 128 h per block
  int h = (blockIdx.x << 7) + hl;                // grid.x = 4
  int c = blockIdx.y, b = blockIdx.z;            // c in 0..NC-2
  float lr[16], li[16], gr[16], gi[16];
#pragma unroll
  for (int j = 0; j < 16; ++j) {
    float4 pp = par[(p * 16 + j) * HH + h];
    lr[j] = pp.x; li[j] = pp.y; gr[j] = 0.f; gi[j] = 0.f;
  }
  const float* Up = U + ((size_t)b * LL + (size_t)c * LC) * HH + h;
  auto step = [&](float uv) {
#pragma unroll
    for (int j = 0; j < 16; ++j) {
      float ngr = fmaf(lr[j], gr[j], fmaf(-li[j], gi[j], uv));
      gi[j] = fmaf(lr[j], gi[j], li[j] * gr[j]);
      gr[j] = ngr;
    }
  };
  float u0 = Up[0], u1 = Up[HH], u2 = Up[2 * HH], u3 = Up[3 * HH];
  float u4 = Up[4 * HH], u5 = Up[5 * HH], u6 = Up[6 * HH], u7 = Up[7 * HH];
  for (int lg = 0; lg < LC / 4; ++lg) {
    const float* nx = Up + (size_t)(lg * 4 + 8) * HH;  // tail lands in ws: harmless
    float v0 = nx[0], v1 = nx[HH], v2 = nx[2 * HH], v3 = nx[3 * HH];
    step(u0); step(u1); step(u2); step(u3);
    u0 = u4; u1 = u5; u2 = u6; u3 = u7;
    u4 = v0; u5 = v1; u6 = v2; u7 = v3;
  }
  size_t so = ((size_t)b * (NC - 1) + c) * (NN2 * HH) + (size_t)(p * 16) * HH + h;
#pragma unroll
  for (int j = 0; j < 16; ++j)
    st[so + (size_t)j * HH] = make_float2(gr[j], gi[j]);
}

// ---------------- fold: prefix-scan chunk states (in place, shifted) -------
// st layout [b][c][n][h]; after: slot c holds raw state at START of chunk c+1.
__global__ __launch_bounds__(256) void k_fold(const float4* __restrict__ par,
    float2* __restrict__ st) {
  int t = blockIdx.x * 256 + threadIdx.x;        // b*16384 + n*512 + h
  int r = t & 16383;
  int b = t >> 14;
  float4 p = par[r];                             // par is [n][h] -> index r
  float ar = p.x, ai = p.y;
#pragma unroll
  for (int s = 0; s < LGLC; ++s) { float nr = ar * ar - ai * ai; ai = 2.f * ar * ai; ar = nr; }  // lam^LC
  float gr = 0.f, gi = 0.f;
  size_t idx = (size_t)b * (NC - 1) * 16384 + r;
  for (int c = 0; c < NC - 1; ++c) {
    float2 s = st[idx + (size_t)c * 16384];
    float ngr = fmaf(ar, gr, fmaf(-ai, gi, s.x));
    gi = fmaf(ar, gi, fmaf(ai, gr, s.y));
    gr = ngr;
    st[idx + (size_t)c * 16384] = make_float2(gr, gi);
  }
}

// ---------------- SSM pass B: thread=(b,c,h,p), g-form, DPP pair-sum -------
// g = lam*g + u; y = Sum (cr*gr - ci*gi); out = act2(y + (D+1)u) -> bf16 hi/lo
__global__ __launch_bounds__(256) void k_sb(const float* __restrict__ U,
    const float4* __restrict__ par, const float2* __restrict__ st,
    const float* __restrict__ D, unsigned short* __restrict__ Hhi,
    unsigned short* __restrict__ Hlo) {
  int tid = threadIdx.x;
  int p = tid & 1, hl = tid >> 1;                // 128 h per block
  int h = (blockIdx.x << 7) + hl;                // grid.x = 4
  int c = blockIdx.y, b = blockIdx.z;            // c in 0..NC-1
  float lr[16], li[16], cr[16], ci[16], gr[16], gi[16];
#pragma unroll
  for (int j = 0; j < 16; ++j) {
    float4 pp = par[(p * 16 + j) * HH + h];
    lr[j] = pp.x; li[j] = pp.y; cr[j] = pp.z; ci[j] = pp.w;
    gr[j] = 0.f; gi[j] = 0.f;
  }
  if (c > 0) {
    size_t so = ((size_t)b * (NC - 1) + (c - 1)) * (NN2 * HH) + (size_t)(p * 16) * HH + h;
#pragma unroll
    for (int j = 0; j < 16; ++j) {
      float2 s = st[so + (size_t)j * HH];
      gr[j] = s.x; gi[j] = s.y;
    }
  }
  float dp1 = D[h] + 1.0f;
  size_t base = ((size_t)b * LL + (size_t)c * LC) * HH + h;
  const float* Up = U + base;
  unsigned short* Hh = Hhi + base;
  unsigned short* Hl = Hlo + base;
  auto step = [&](float uv) -> float {
    float ya = 0.f, yb = 0.f, yc = 0.f, yd = 0.f;
#pragma unroll
    for (int j = 0; j < 16; ++j) {
      float ngr = fmaf(lr[j], gr[j], fmaf(-li[j], gi[j], uv));
      gi[j] = fmaf(lr[j], gi[j], li[j] * gr[j]);
      gr[j] = ngr;
      if (j & 1) { ya = fmaf(cr[j], gr[j], ya); yb = fmaf(ci[j], gi[j], yb); }
      else       { yc = fmaf(cr[j], gr[j], yc); yd = fmaf(ci[j], gi[j], yd); }
    }
    float ys = pairsum((ya + yc) - (yb + yd));   // partner lane: other 16 states
    float t4 = fmaf(dp1, uv, ys);
    return t4 < 0.f ? 2.f * t4 : 4.f * t4;
  };
  float u0 = Up[0], u1 = Up[HH], u2 = Up[2 * HH], u3 = Up[3 * HH];
  float u4 = Up[4 * HH], u5 = Up[5 * HH], u6 = Up[6 * HH], u7 = Up[7 * HH];
  for (int lg = 0; lg < LC / 4; ++lg) {
    const float* nx = Up + (size_t)(lg * 4 + 8) * HH;  // tail lands in ws: harmless
    float v0 = nx[0], v1 = nx[HH], v2 = nx[2 * HH], v3 = nx[3 * HH];
    float r0 = step(u0), r1 = step(u1), r2 = step(u2), r3 = step(u3);
    // lane parity p stores steps 4lg+p and 4lg+2+p (both lanes hold all r's)
    size_t o = (size_t)(lg * 4) * HH;
    float ra = p ? r1 : r0;
    float rb = p ? r3 : r2;
    unsigned short ha = f2bf(ra), hb = f2bf(rb);
    Hh[o + (size_t)p * HH] = ha;
    Hh[o + (size_t)(2 + p) * HH] = hb;
    Hl[o + (size_t)p * HH] = f2bf(ra - bf2f(ha));
    Hl[o + (size_t)(2 + p) * HH] = f2bf(rb - bf2f(hb));
    u0 = u4; u1 = u5; u2 = u6; u3 = u7;
    u4 = v0; u5 = v1; u6 = v2; u7 = v3;
  }
}

// ---------------------------------------------------------------------------
extern "C" void kernel_launch(void* const* d_in, const int* in_sizes, int n_in,
                              void* d_out, int out_size, void* d_ws, size_t ws_size,
                              hipStream_t stream) {
  const int*   x      = (const int*)d_in[0];
  const float* emb    = (const float*)d_in[1];
  const float* Ws     = (const float*)d_in[2];
  const float* bs     = (const float*)d_in[3];
  const float* log_dt = (const float*)d_in[4];
  const float* lAr    = (const float*)d_in[5];
  const float* Aim    = (const float*)d_in[6];
  const float* Cre    = (const float*)d_in[7];
  const float* Cim    = (const float*)d_in[8];
  const float* Ds     = (const float*)d_in[9];
  const float* Wo     = (const float*)d_in[10];
  const float* bo     = (const float*)d_in[11];

  float*          bufU   = (float*)d_ws;                       // 67.1 MB
  unsigned short* bufAhi = (unsigned short*)(bufU + NELEM);    // 33.6 MB
  unsigned short* bufAlo = bufAhi + NELEM;                     // 33.6 MB
  float4*         par    = (float4*)(bufAlo + NELEM);          // 256 KB
  float2*         st     = (float2*)(par + HH * NN2);          // 31.5 MB
  unsigned short* wth    = (unsigned short*)(st + (size_t)BB * (NC - 1) * HH * NN2);  // 512 KB
  unsigned short* wtl    = wth + 512 * 512;                    // 512 KB

  k_embed<<<(int)(NELEM / 4 / 256), 256, 0, stream>>>(x, emb, bufAhi, bufAlo);
  for (int i = 0; i < NLAY; ++i) {
    k_params<<<HH * NN2 / 256, 256, 0, stream>>>(log_dt, lAr, Aim, Cre, Cim, i, par);
    k_trans<<<HH * 512 / 256, 256, 0, stream>>>(Ws + (size_t)i * HH * HH, HH, wth, wtl, 1);
    k_gemm<1><<<dim3(HH / 128, BLM / 128), 256, 0, stream>>>(
        bufAhi, bufAlo, wth, wtl, bs + i * HH, bufU, HH);
    k_sa<<<dim3(4, NC - 1, BB), 256, 0, stream>>>(bufU, par, st);
    k_fold<<<BB * HH * NN2 / 256, 256, 0, stream>>>(par, st);
    k_sb<<<dim3(4, NC, BB), 256, 0, stream>>>(bufU, par, st, Ds + i * HH, bufAhi, bufAlo);
  }
  k_trans<<<OUTD * 512 / 256, 256, 0, stream>>>(Wo, OUTD, wth, wtl, 0);
  k_gemm<0><<<dim3(OUTD / 128, BLM / 128), 256, 0, stream>>>(
      bufAhi, bufAlo, wth, wtl, bo, (float*)d_out, OUTD);
}